// Round 3
// baseline (888.685 us; speedup 1.0000x reference)
//
#include <hip/hip_runtime.h>
#include <hip/hip_fp16.h>

#define B_ 256
#define T_ 200
#define H_ 256
#define G3 768            // 3*H
#define NV 50001          // V+1

typedef _Float16 half2v __attribute__((ext_vector_type(2)));
typedef _Float16 half4v __attribute__((ext_vector_type(4)));
typedef _Float16 half8v __attribute__((ext_vector_type(8)));
typedef float f32x4 __attribute__((ext_vector_type(4)));

union U32H2 { unsigned int u; half2v h; };

__device__ __forceinline__ float sigmoidf_(float x) {
  return 1.f / (1.f + __expf(-x));
}
__device__ __forceinline__ float tanhf_(float x) {
  float ax = fabsf(x);
  float e = __expf(-2.f * ax);
  float t = (1.f - e) / (1.f + e);
  return copysignf(t, x);
}
__device__ __forceinline__ f32x4 mfma16(half8v a, half8v b, f32x4 c) {
  return __builtin_amdgcn_mfma_f32_16x16x32_f16(a, b, c, 0, 0, 0);
}

// ---- pack w_hh [256][768] fp32 -> MFMA B-fragment-linear fp16:
// frag f = nt*8+kc (nt in [0,48), kc in [0,8)); within frag: lane (64) x 8 halfs.
// half j of lane l of frag (nt,kc) = w_hh[kc*32 + (l>>4)*8 + j][nt*16 + (l&15)].
// One u32 = halfs (2jp, 2jp+1). Loads in rec are then lane-contiguous dwordx4.
__global__ __launch_bounds__(256) void pack_whh_frag(
    const float* __restrict__ whh, unsigned int* __restrict__ out) {
  int idx = blockIdx.x * 256 + threadIdx.x;   // 0..98303
  int f = idx >> 8;                           // nt*8+kc
  int rem = idx & 255;
  int lane = rem >> 2;
  int jp = rem & 3;
  int nt = f >> 3, kc = f & 7;
  int col = nt * 16 + (lane & 15);
  int k = kc * 32 + (lane >> 4) * 8 + jp * 2;
  U32H2 u;
  u.h.x = (_Float16)whh[(size_t)k * G3 + col];
  u.h.y = (_Float16)whh[(size_t)(k + 1) * G3 + col];
  out[idx] = u.u;
}

// ---- pack w_ih -> transposed fp16 [768 cols][256 k] (gates_mfma B staging).
__global__ __launch_bounds__(256) void pack_wiht(
    const float* __restrict__ wih, unsigned int* __restrict__ out) {
  int idx = blockIdx.x * 256 + threadIdx.x;   // 0..98303
  int col = idx >> 7;
  int kk = (idx & 127) * 2;
  U32H2 u;
  u.h.x = (_Float16)wih[(size_t)kk * G3 + col];
  u.h.y = (_Float16)wih[(size_t)(kk + 1) * G3 + col];
  out[idx] = u.u;
}

// ---- K1: gates = emb[ids] @ w_ih + b_ih via f16 MFMA.
// Row order m' = t*256 + b (so t = m'>>8, b = m'&255: cheap bit ops).
// Output layout: gates[((t*16 + bg)*768 + col)*16 + ri], bg = b>>4, ri = b&15
// -> rec_mfma's per-lane 4-row gate reads are contiguous 8B.
__global__ __launch_bounds__(512) void gates_mfma(
    const int* __restrict__ ids, const float* __restrict__ emb,
    const __half* __restrict__ wih_t, const float* __restrict__ b_ih,
    __half* __restrict__ gates) {
  __shared__ __align__(16) _Float16 As[128 * 72];   // [row][k] stride 72
  __shared__ __align__(16) _Float16 Bs[256 * 72];   // [col][k] stride 72
  __shared__ int ids_s[128];
  __shared__ float bs[256];
  const int tid = threadIdx.x;
  const int t = blockIdx.x >> 1;                 // 128-row block within one t
  const int bbase0 = (blockIdx.x & 1) * 128;
  const int c0 = blockIdx.y * 256;
  const int w = tid >> 6, lane = tid & 63;
  const int wm = w >> 2, wn = w & 3;
  const int lr = lane & 15, lk = lane >> 4;

  if (tid < 128) ids_s[tid] = ids[(bbase0 + tid) * T_ + t];
  if (tid < 256) bs[tid] = b_ih[c0 + tid];
  __syncthreads();

  f32x4 acc[4][4];
#pragma unroll
  for (int i = 0; i < 4; ++i)
#pragma unroll
    for (int j = 0; j < 4; ++j) acc[i][j] = (f32x4){0.f, 0.f, 0.f, 0.f};

  for (int c = 0; c < 4; ++c) {
    const int kc = c * 64;
    // A: gather 128 emb rows x 64 k fp32 -> f16
#pragma unroll
    for (int r4 = 0; r4 < 4; ++r4) {
      int q = tid + r4 * 512;
      int row = q >> 4;
      int kk = (q & 15) * 4;
      const float4 v = *(const float4*)&emb[(size_t)ids_s[row] * H_ + kc + kk];
      half4v hv = {(_Float16)v.x, (_Float16)v.y, (_Float16)v.z, (_Float16)v.w};
      *(half4v*)&As[row * 72 + kk] = hv;
    }
    // B: 256 cols x 64 k from pre-transposed fp16 w_ih
#pragma unroll
    for (int r4 = 0; r4 < 4; ++r4) {
      int q = tid + r4 * 512;
      int col = q >> 3;
      int cc = q & 7;
      uint4 v = *(const uint4*)((const unsigned short*)wih_t +
                                (size_t)(c0 + col) * H_ + kc + cc * 8);
      *(uint4*)&Bs[col * 72 + cc * 8] = v;
    }
    __syncthreads();
#pragma unroll
    for (int ks = 0; ks < 2; ++ks) {
      half8v af[4], bf[4];
#pragma unroll
      for (int i = 0; i < 4; ++i)
        af[i] = *(const half8v*)&As[(wm * 64 + i * 16 + lr) * 72 + ks * 32 + lk * 8];
#pragma unroll
      for (int j = 0; j < 4; ++j)
        bf[j] = *(const half8v*)&Bs[(wn * 64 + j * 16 + lr) * 72 + ks * 32 + lk * 8];
#pragma unroll
      for (int i = 0; i < 4; ++i)
#pragma unroll
        for (int j = 0; j < 4; ++j)
          acc[i][j] = mfma16(af[i], bf[j], acc[i][j]);
    }
    __syncthreads();
  }
  // store in rec-friendly layout (4 rows contiguous -> b64 stores)
  const int bgb = (bbase0 + wm * 64) >> 4;
#pragma unroll
  for (int j = 0; j < 4; ++j) {
    const int col = c0 + wn * 64 + j * 16 + lr;
    const float bj = bs[wn * 64 + j * 16 + lr];
#pragma unroll
    for (int i = 0; i < 4; ++i) {
      size_t base = ((size_t)((t * 16 + bgb + i) * 768 + col)) * 16 + lk * 4;
      half4v hv = {(_Float16)(acc[i][j][0] + bj), (_Float16)(acc[i][j][1] + bj),
                   (_Float16)(acc[i][j][2] + bj), (_Float16)(acc[i][j][3] + bj)};
      *(half4v*)&gates[base] = hv;
    }
  }
}

// ---- K2: GRU recurrence via MFMA. 16 WGs x 512 thr; WG owns 16 batch rows.
// w_hh: kc 0..5 register-resident B-frags (144 VGPR), kc 6..7 persistent LDS.
// Wave w owns col-blocks {2w,2w+1} for ALL 3 gates -> in-register h-update.
__global__ __launch_bounds__(512, 2) __attribute__((amdgpu_waves_per_eu(2, 2)))
void rec_mfma(const int* __restrict__ lens,
              const unsigned int* __restrict__ whh_f,
              const float* __restrict__ b_hh,
              const __half* __restrict__ gates, float* __restrict__ hfin) {
  __shared__ _Float16 h_lds[16 * 264];                 // row stride 528 B
  __shared__ __align__(16) unsigned int Bw[24576];     // 96 KB: kc 6,7 frags
  const int tid = threadIdx.x;
  const int bg = blockIdx.x;
  const int w = tid >> 6, lane = tid & 63;
  const int lr = lane & 15, lk = lane >> 4;

  // register-resident weight fragments (kc 0..5)
  half8v Wr[3][2][6];
#pragma unroll
  for (int g = 0; g < 3; ++g)
#pragma unroll
    for (int cb = 0; cb < 2; ++cb) {
      int nt = g * 16 + w * 2 + cb;
#pragma unroll
      for (int kc = 0; kc < 6; ++kc) {
        uint4 v = *(const uint4*)&whh_f[((nt * 8 + kc) * 64 + lane) * 4];
        Wr[g][cb][kc] = __builtin_bit_cast(half8v, v);
      }
    }
  // keep-alive: make the loads un-rematerializable so they stay resident
#pragma unroll
  for (int g = 0; g < 3; ++g)
#pragma unroll
    for (int cb = 0; cb < 2; ++cb)
#pragma unroll
      for (int kc = 0; kc < 6; ++kc)
        asm volatile("" : "+v"(Wr[g][cb][kc]));

  // stage kc 6,7 fragments into LDS (lane-linear: conflict-free b128)
#pragma unroll
  for (int p = 0; p < 6; ++p)
#pragma unroll
    for (int q = 0; q < 2; ++q) {
      int g = p >> 1, cb = p & 1;
      int nt = g * 16 + w * 2 + cb;
      uint4 v = *(const uint4*)&whh_f[((nt * 8 + 6 + q) * 64 + lane) * 4];
      *(uint4*)&Bw[(((w * 6 + p) * 2 + q) * 64 + lane) * 4] = v;
    }
  // zero h state
  for (int i = tid; i < 16 * 132; i += 512) ((unsigned int*)h_lds)[i] = 0;

  int len_r[4];
#pragma unroll
  for (int r = 0; r < 4; ++r) len_r[r] = lens[bg * 16 + lk * 4 + r];
  int lmax = 0;
  for (int i = 0; i < 16; ++i) lmax = max(lmax, lens[bg * 16 + i]);

  float bhh[3][2];
  int goff[3][2];
#pragma unroll
  for (int g = 0; g < 3; ++g)
#pragma unroll
    for (int cb = 0; cb < 2; ++cb) {
      int col = g * 256 + w * 32 + cb * 16 + lr;
      bhh[g][cb] = b_hh[col];
      goff[g][cb] = col * 16 + lk * 4;
    }
  float h_old[2][4];
#pragma unroll
  for (int cb = 0; cb < 2; ++cb)
#pragma unroll
    for (int r = 0; r < 4; ++r) h_old[cb][r] = 0.f;
  __syncthreads();

  const __half* gbase = gates + (size_t)bg * 12288;
  for (int t = 0; t < lmax; ++t) {
    const __half* gt = gbase + (size_t)t * 196608;   // 16*768*16 halfs/step
    half4v gx[3][2];
#pragma unroll
    for (int g = 0; g < 3; ++g)
#pragma unroll
      for (int cb = 0; cb < 2; ++cb)
        gx[g][cb] = *(const half4v*)(gt + goff[g][cb]);

    f32x4 acc[3][2];
#pragma unroll
    for (int g = 0; g < 3; ++g)
#pragma unroll
      for (int cb = 0; cb < 2; ++cb)
        acc[g][cb] = (f32x4){bhh[g][cb], bhh[g][cb], bhh[g][cb], bhh[g][cb]};

#pragma unroll
    for (int kc = 0; kc < 6; ++kc) {
      half8v a = *(const half8v*)&h_lds[lr * 264 + kc * 32 + lk * 8];
#pragma unroll
      for (int g = 0; g < 3; ++g)
#pragma unroll
        for (int cb = 0; cb < 2; ++cb)
          acc[g][cb] = mfma16(a, Wr[g][cb][kc], acc[g][cb]);
    }
#pragma unroll
    for (int q = 0; q < 2; ++q) {
      half8v a = *(const half8v*)&h_lds[lr * 264 + (6 + q) * 32 + lk * 8];
#pragma unroll
      for (int p = 0; p < 6; ++p) {
        int g = p >> 1, cb = p & 1;
        half8v bw = *(const half8v*)&Bw[(((w * 6 + p) * 2 + q) * 64 + lane) * 4];
        acc[g][cb] = mfma16(a, bw, acc[g][cb]);
      }
    }
    // in-register GRU update (lane owns z,r,hh for its 8 (row,col) elems)
#pragma unroll
    for (int cb = 0; cb < 2; ++cb)
#pragma unroll
      for (int r = 0; r < 4; ++r) {
        float z = sigmoidf_((float)gx[0][cb][r] + acc[0][cb][r]);
        float rr = sigmoidf_((float)gx[1][cb][r] + acc[1][cb][r]);
        float hh = tanhf_((float)gx[2][cb][r] + rr * acc[2][cb][r]);
        float hv = z * h_old[cb][r] + (1.f - z) * hh;
        if (t < len_r[r]) h_old[cb][r] = hv;
      }
    __syncthreads();   // all waves' A-reads complete before h rewrite
#pragma unroll
    for (int cb = 0; cb < 2; ++cb) {
      int colh = w * 32 + cb * 16 + lr;
#pragma unroll
      for (int r = 0; r < 4; ++r)
        h_lds[(lk * 4 + r) * 264 + colh] = (_Float16)h_old[cb][r];
    }
    __syncthreads();
  }
#pragma unroll
  for (int cb = 0; cb < 2; ++cb)
#pragma unroll
    for (int r = 0; r < 4; ++r)
      hfin[(size_t)(bg * 16 + lk * 4 + r) * H_ + w * 32 + cb * 16 + lr] =
          h_old[cb][r];
}

// ---- K3: logits = hfin @ emb^T via hi/lo-split f16 MFMA (fp32-class accuracy).
__global__ __launch_bounds__(512) void logits_mfma(
    const float* __restrict__ hfin, const float* __restrict__ emb,
    float* __restrict__ out) {
  __shared__ __align__(16) _Float16 As[256 * 72];
  __shared__ __align__(16) _Float16 Bs[64 * 72];
  const int tid = threadIdx.x;
  const int n0 = blockIdx.x * 64;
  const int w = tid >> 6, lane = tid & 63;
  const int wm = w >> 1, wn = w & 1;
  const int lr = lane & 15, lk = lane >> 4;

  f32x4 a1[4][2], a2[4][2];
#pragma unroll
  for (int i = 0; i < 4; ++i)
#pragma unroll
    for (int j = 0; j < 2; ++j) {
      a1[i][j] = (f32x4){0.f, 0.f, 0.f, 0.f};
      a2[i][j] = (f32x4){0.f, 0.f, 0.f, 0.f};
    }

  for (int c = 0; c < 8; ++c) {
    const int kc = c * 32;
#pragma unroll
    for (int r4 = 0; r4 < 4; ++r4) {
      int q = tid + r4 * 512;
      int row = q >> 3;
      int kk = (q & 7) * 4;
      float4 v = *(const float4*)&hfin[(size_t)row * H_ + kc + kk];
      half4v hi = {(_Float16)v.x, (_Float16)v.y, (_Float16)v.z, (_Float16)v.w};
      half4v lo = {(_Float16)((v.x - (float)hi.x) * 1024.f),
                   (_Float16)((v.y - (float)hi.y) * 1024.f),
                   (_Float16)((v.z - (float)hi.z) * 1024.f),
                   (_Float16)((v.w - (float)hi.w) * 1024.f)};
      int base = row * 72 + (kk >> 3) * 16 + (kk & 7);
      *(half4v*)&As[base] = hi;
      *(half4v*)&As[base + 8] = lo;
    }
    {
      int col = tid >> 3;
      int kk = (tid & 7) * 4;
      int n = n0 + col;
      float4 v = (n < NV) ? *(const float4*)&emb[(size_t)n * H_ + kc + kk]
                          : make_float4(0.f, 0.f, 0.f, 0.f);
      half4v hi = {(_Float16)v.x, (_Float16)v.y, (_Float16)v.z, (_Float16)v.w};
      half4v lo = {(_Float16)((v.x - (float)hi.x) * 1024.f),
                   (_Float16)((v.y - (float)hi.y) * 1024.f),
                   (_Float16)((v.z - (float)hi.z) * 1024.f),
                   (_Float16)((v.w - (float)hi.w) * 1024.f)};
      int base = col * 72 + (kk >> 3) * 16 + (kk & 7);
      *(half4v*)&Bs[base] = hi;
      *(half4v*)&Bs[base + 8] = lo;
    }
    __syncthreads();
    half8v ah[4], al[4];
#pragma unroll
    for (int i = 0; i < 4; ++i) {
      int base = (wm * 64 + i * 16 + lr) * 72 + lk * 16;
      ah[i] = *(const half8v*)&As[base];
      al[i] = *(const half8v*)&As[base + 8];
    }
#pragma unroll
    for (int j = 0; j < 2; ++j) {
      int base = (wn * 32 + j * 16 + lr) * 72 + lk * 16;
      half8v bh = *(const half8v*)&Bs[base];
      half8v bl = *(const half8v*)&Bs[base + 8];
#pragma unroll
      for (int i = 0; i < 4; ++i) {
        a1[i][j] = mfma16(ah[i], bh, a1[i][j]);
        a2[i][j] = mfma16(ah[i], bl, a2[i][j]);
        a2[i][j] = mfma16(al[i], bh, a2[i][j]);
      }
    }
    __syncthreads();
  }
#pragma unroll
  for (int j = 0; j < 2; ++j) {
    int n = n0 + wn * 32 + j * 16 + lr;
    if (n < NV) {
#pragma unroll
      for (int i = 0; i < 4; ++i) {
        int row = wm * 64 + i * 16 + lk * 4;
#pragma unroll
        for (int r = 0; r < 4; ++r)
          out[(size_t)(row + r) * NV + n] =
              a1[i][j][r] + a2[i][j][r] * (1.f / 1024.f);
      }
    }
  }
}

extern "C" void kernel_launch(void* const* d_in, const int* in_sizes, int n_in,
                              void* d_out, int out_size, void* d_ws, size_t ws_size,
                              hipStream_t stream) {
  const int* ids = (const int*)d_in[0];
  const int* lens = (const int*)d_in[1];
  const float* emb = (const float*)d_in[2];
  const float* w_ih = (const float*)d_in[3];
  const float* w_hh = (const float*)d_in[4];
  const float* b_ih = (const float*)d_in[5];
  const float* b_hh = (const float*)d_in[6];
  float* out = (float*)d_out;

  char* ws = (char*)d_ws;
  __half* gates = (__half*)ws;                           // 78,643,200 B
  float* hfin = (float*)(ws + (size_t)B_ * T_ * G3 * sizeof(__half));
  unsigned int* whh_f =
      (unsigned int*)(ws + (size_t)B_ * T_ * G3 * sizeof(__half)
                      + (size_t)B_ * H_ * sizeof(float));   // 393,216 B
  unsigned int* wih_t = whh_f + (size_t)98304;              // 393,216 B

  pack_whh_frag<<<dim3(384), dim3(256), 0, stream>>>(w_hh, whh_f);
  pack_wiht<<<dim3(384), dim3(256), 0, stream>>>(w_ih, wih_t);
  gates_mfma<<<dim3(400, 3), dim3(512), 0, stream>>>(
      ids, emb, (const __half*)wih_t, b_ih, gates);
  rec_mfma<<<dim3(16), dim3(512), 0, stream>>>(lens, whh_f, b_hh, gates, hfin);
  logits_mfma<<<dim3((NV + 63) / 64), dim3(512), 0, stream>>>(hfin, emb, out);
}

// Round 4
// 467.730 us; speedup vs baseline: 1.9000x; 1.9000x over previous
//
#include <hip/hip_runtime.h>
#include <hip/hip_fp16.h>

#define B_ 256
#define T_ 200
#define H_ 256
#define G3 768            // 3*H
#define NV 50001          // V+1
#define SP 80             // rec: K-pairs streamed from global per step
#define LP 48             // rec: K-pairs persistent in LDS

typedef _Float16 half2v __attribute__((ext_vector_type(2)));
typedef _Float16 half4v __attribute__((ext_vector_type(4)));
typedef _Float16 half8v __attribute__((ext_vector_type(8)));
typedef float f32x4 __attribute__((ext_vector_type(4)));

union U32H2 { unsigned int u; half2v h; };

__device__ __forceinline__ float fdot2(half2v a, half2v b, float c) {
  return __builtin_amdgcn_fdot2(a, b, c, false);
}
__device__ __forceinline__ float sigmoidf_(float x) {
  return 1.f / (1.f + __expf(-x));
}
__device__ __forceinline__ float tanhf_(float x) {
  float ax = fabsf(x);
  float e = __expf(-2.f * ax);
  float t = (1.f - e) / (1.f + e);
  return copysignf(t, x);
}
__device__ __forceinline__ f32x4 mfma16(half8v a, half8v b, f32x4 c) {
  return __builtin_amdgcn_mfma_f32_16x16x32_f16(a, b, c, 0, 0, 0);
}

// ---- pack w_hh -> K-pair-packed fp16: out[p*768+col] = (w[2p][col], w[2p+1][col]).
__global__ __launch_bounds__(256) void pack_whh(
    const float* __restrict__ whh, unsigned int* __restrict__ out) {
  int idx = blockIdx.x * 256 + threadIdx.x;     // 0..98303
  int p = idx / G3;
  int col = idx - p * G3;
  U32H2 u;
  u.h.x = (_Float16)whh[(size_t)(2 * p) * G3 + col];
  u.h.y = (_Float16)whh[(size_t)(2 * p + 1) * G3 + col];
  out[idx] = u.u;
}

// ---- pack w_ih -> transposed fp16 [768 cols][256 k] (gates_mfma B staging).
__global__ __launch_bounds__(256) void pack_wiht(
    const float* __restrict__ wih, unsigned int* __restrict__ out) {
  int idx = blockIdx.x * 256 + threadIdx.x;     // 0..98303
  int col = idx >> 7;
  int kk = (idx & 127) * 2;
  U32H2 u;
  u.h.x = (_Float16)wih[(size_t)kk * G3 + col];
  u.h.y = (_Float16)wih[(size_t)(kk + 1) * G3 + col];
  out[idx] = u.u;
}

// ---- K1: gates = emb[ids] @ w_ih + b_ih via f16 MFMA (round-2, measured).
__global__ __launch_bounds__(512) void gates_mfma(
    const int* __restrict__ ids, const float* __restrict__ emb,
    const __half* __restrict__ wih_t, const float* __restrict__ b_ih,
    __half* __restrict__ gates) {
  __shared__ __align__(16) _Float16 As[128 * 72];   // [row][k] stride 72
  __shared__ __align__(16) _Float16 Bs[256 * 72];   // [col][k] stride 72
  __shared__ int ids_s[128];
  __shared__ float bs[256];
  const int tid = threadIdx.x;
  const int r0 = blockIdx.x * 128;
  const int c0 = blockIdx.y * 256;
  const int w = tid >> 6, lane = tid & 63;
  const int wm = w >> 2, wn = w & 3;
  const int lr = lane & 15, lk = lane >> 4;

  if (tid < 128) ids_s[tid] = ids[r0 + tid];
  if (tid < 256) bs[tid] = b_ih[c0 + tid];
  __syncthreads();

  f32x4 acc[4][4];
#pragma unroll
  for (int i = 0; i < 4; ++i)
#pragma unroll
    for (int j = 0; j < 4; ++j) acc[i][j] = (f32x4){0.f, 0.f, 0.f, 0.f};

  for (int c = 0; c < 4; ++c) {
    const int kc = c * 64;
#pragma unroll
    for (int r4 = 0; r4 < 4; ++r4) {
      int q = tid + r4 * 512;
      int row = q >> 4;
      int kk = (q & 15) * 4;
      const float4 v = *(const float4*)&emb[(size_t)ids_s[row] * H_ + kc + kk];
      half4v hv = {(_Float16)v.x, (_Float16)v.y, (_Float16)v.z, (_Float16)v.w};
      *(half4v*)&As[row * 72 + kk] = hv;
    }
#pragma unroll
    for (int r4 = 0; r4 < 4; ++r4) {
      int q = tid + r4 * 512;
      int col = q >> 3;
      int cc = q & 7;
      uint4 v = *(const uint4*)((const unsigned short*)wih_t +
                                (size_t)(c0 + col) * H_ + kc + cc * 8);
      *(uint4*)&Bs[col * 72 + cc * 8] = v;
    }
    __syncthreads();
#pragma unroll
    for (int ks = 0; ks < 2; ++ks) {
      half8v af[4], bf[4];
#pragma unroll
      for (int i = 0; i < 4; ++i)
        af[i] = *(const half8v*)&As[(wm * 64 + i * 16 + lr) * 72 + ks * 32 + lk * 8];
#pragma unroll
      for (int j = 0; j < 4; ++j)
        bf[j] = *(const half8v*)&Bs[(wn * 64 + j * 16 + lr) * 72 + ks * 32 + lk * 8];
#pragma unroll
      for (int i = 0; i < 4; ++i)
#pragma unroll
        for (int j = 0; j < 4; ++j)
          acc[i][j] = mfma16(af[i], bf[j], acc[i][j]);
    }
    __syncthreads();
  }
#pragma unroll
  for (int j = 0; j < 4; ++j) {
    const int col = c0 + wn * 64 + j * 16 + lr;
    const float bj = bs[wn * 64 + j * 16 + lr];
#pragma unroll
    for (int i = 0; i < 4; ++i) {
      const int row = r0 + wm * 64 + i * 16 + lk * 4;
#pragma unroll
      for (int r = 0; r < 4; ++r)
        gates[(size_t)(row + r) * G3 + col] = (__half)(acc[i][j][r] + bj);
    }
  }
}

// ---- rec dot: 80 pairs from register/stream path + 48 pairs from LDS pipe.
__device__ __forceinline__ float dot_dual(const half2v (&W)[SP],
                                          const unsigned int* __restrict__ Wl,
                                          int tid,
                                          const unsigned int* __restrict__ x) {
  float a0 = 0.f, a1 = 0.f;
  const uint4* hx = (const uint4*)x;
  const uint4* wl4 = (const uint4*)Wl;
#pragma unroll
  for (int p4 = 0; p4 < SP / 4; ++p4) {
    uint4 v = hx[p4];
    U32H2 c0, c1, c2, c3;
    c0.u = v.x; c1.u = v.y; c2.u = v.z; c3.u = v.w;
    a0 = fdot2(W[4 * p4 + 0], c0.h, a0);
    a1 = fdot2(W[4 * p4 + 1], c1.h, a1);
    a0 = fdot2(W[4 * p4 + 2], c2.h, a0);
    a1 = fdot2(W[4 * p4 + 3], c3.h, a1);
  }
#pragma unroll
  for (int q = 0; q < LP / 4; ++q) {
    uint4 wv = wl4[(size_t)q * G3 + tid];   // lane-stride 16B, bandwidth-bound
    uint4 v = hx[SP / 4 + q];
    U32H2 c0, c1, c2, c3, w0, w1, w2, w3;
    c0.u = v.x; c1.u = v.y; c2.u = v.z; c3.u = v.w;
    w0.u = wv.x; w1.u = wv.y; w2.u = wv.z; w3.u = wv.w;
    a0 = fdot2(w0.h, c0.h, a0);
    a1 = fdot2(w1.h, c1.h, a1);
    a0 = fdot2(w2.h, c2.h, a0);
    a1 = fdot2(w3.h, c3.h, a1);
  }
  return a0 + a1;
}

// ---- K2: GRU recurrence, 256 WGs x 768 thr (round-0 structure + dual-pipe).
__global__ __launch_bounds__(768, 3) void rec_kernel(
    const int* __restrict__ lens, const unsigned int* __restrict__ whh_p,
    const float* __restrict__ b_hh, const __half* __restrict__ gates,
    float* __restrict__ hfin) {
  __shared__ float rec[G3];
  __shared__ __half hpk[256];
  __shared__ __align__(16) unsigned int Wl[LP * G3];   // 147 KB: pairs 80..127
  const int tid = threadIdx.x;
  const int b = blockIdx.x;

  // pairs 0..79: registers (80 + ~40 working < 170 budget at 3 waves/EU)
  half2v W[SP];
#pragma unroll
  for (int p = 0; p < SP; ++p) {
    U32H2 u;
    u.u = whh_p[(size_t)p * G3 + tid];
    W[p] = u.h;
  }
#pragma unroll
  for (int p = 0; p < SP; ++p) asm volatile("" : "+v"(W[p]));

  // pairs 80..127 -> LDS, layout [q][col][4]: uint4 per (q,col)
#pragma unroll
  for (int q = 0; q < LP / 4; ++q) {
    uint4 v;
    v.x = whh_p[(size_t)(SP + 4 * q + 0) * G3 + tid];
    v.y = whh_p[(size_t)(SP + 4 * q + 1) * G3 + tid];
    v.z = whh_p[(size_t)(SP + 4 * q + 2) * G3 + tid];
    v.w = whh_p[(size_t)(SP + 4 * q + 3) * G3 + tid];
    *(uint4*)&Wl[(size_t)q * (4 * G3) + tid * 4] = v;
  }

  const int len = lens[b];
  float bh0 = 0.f, bh1 = 0.f, bh2 = 0.f;
  float h = 0.f;
  if (tid < 256) {
    bh0 = b_hh[tid];
    bh1 = b_hh[256 + tid];
    bh2 = b_hh[512 + tid];
    hpk[tid] = (__half)0.f;
  }
  __syncthreads();

  const __half* gp = gates + (size_t)b * T_ * G3 + tid;
  for (int t = 0; t < len; ++t) {
    float gxz = 0.f, gxr = 0.f, gxh = 0.f;
    if (tid < 256) {  // prefetch; consumed after the barrier
      const __half* gpt = gp + (size_t)t * G3;
      gxz = (float)gpt[0];
      gxr = (float)gpt[256];
      gxh = (float)gpt[512];
    }
    float d = dot_dual(W, Wl, tid, (const unsigned int*)&hpk[0]);
    rec[tid] = d;
    __syncthreads();
    if (tid < 256) {
      float z = sigmoidf_(gxz + rec[tid] + bh0);
      float r = sigmoidf_(gxr + rec[256 + tid] + bh1);
      float hh = tanhf_(gxh + r * (rec[512 + tid] + bh2));
      h = z * h + (1.f - z) * hh;
      hpk[tid] = (__half)h;
    }
    __syncthreads();
  }
  if (tid < 256) hfin[(size_t)b * H_ + tid] = h;
}

// ---- K3: logits = hfin @ emb^T via hi/lo-split f16 MFMA (round-2, measured).
__global__ __launch_bounds__(512) void logits_mfma(
    const float* __restrict__ hfin, const float* __restrict__ emb,
    float* __restrict__ out) {
  __shared__ __align__(16) _Float16 As[256 * 72];
  __shared__ __align__(16) _Float16 Bs[64 * 72];
  const int tid = threadIdx.x;
  const int n0 = blockIdx.x * 64;
  const int w = tid >> 6, lane = tid & 63;
  const int wm = w >> 1, wn = w & 1;
  const int lr = lane & 15, lk = lane >> 4;

  f32x4 a1[4][2], a2[4][2];
#pragma unroll
  for (int i = 0; i < 4; ++i)
#pragma unroll
    for (int j = 0; j < 2; ++j) {
      a1[i][j] = (f32x4){0.f, 0.f, 0.f, 0.f};
      a2[i][j] = (f32x4){0.f, 0.f, 0.f, 0.f};
    }

  for (int c = 0; c < 8; ++c) {
    const int kc = c * 32;
#pragma unroll
    for (int r4 = 0; r4 < 4; ++r4) {
      int q = tid + r4 * 512;
      int row = q >> 3;
      int kk = (q & 7) * 4;
      float4 v = *(const float4*)&hfin[(size_t)row * H_ + kc + kk];
      half4v hi = {(_Float16)v.x, (_Float16)v.y, (_Float16)v.z, (_Float16)v.w};
      half4v lo = {(_Float16)((v.x - (float)hi.x) * 1024.f),
                   (_Float16)((v.y - (float)hi.y) * 1024.f),
                   (_Float16)((v.z - (float)hi.z) * 1024.f),
                   (_Float16)((v.w - (float)hi.w) * 1024.f)};
      int base = row * 72 + (kk >> 3) * 16 + (kk & 7);
      *(half4v*)&As[base] = hi;
      *(half4v*)&As[base + 8] = lo;
    }
    {
      int col = tid >> 3;
      int kk = (tid & 7) * 4;
      int n = n0 + col;
      float4 v = (n < NV) ? *(const float4*)&emb[(size_t)n * H_ + kc + kk]
                          : make_float4(0.f, 0.f, 0.f, 0.f);
      half4v hi = {(_Float16)v.x, (_Float16)v.y, (_Float16)v.z, (_Float16)v.w};
      half4v lo = {(_Float16)((v.x - (float)hi.x) * 1024.f),
                   (_Float16)((v.y - (float)hi.y) * 1024.f),
                   (_Float16)((v.z - (float)hi.z) * 1024.f),
                   (_Float16)((v.w - (float)hi.w) * 1024.f)};
      int base = col * 72 + (kk >> 3) * 16 + (kk & 7);
      *(half4v*)&Bs[base] = hi;
      *(half4v*)&Bs[base + 8] = lo;
    }
    __syncthreads();
    half8v ah[4], al[4];
#pragma unroll
    for (int i = 0; i < 4; ++i) {
      int base = (wm * 64 + i * 16 + lr) * 72 + lk * 16;
      ah[i] = *(const half8v*)&As[base];
      al[i] = *(const half8v*)&As[base + 8];
    }
#pragma unroll
    for (int j = 0; j < 2; ++j) {
      int base = (wn * 32 + j * 16 + lr) * 72 + lk * 16;
      half8v bh = *(const half8v*)&Bs[base];
      half8v bl = *(const half8v*)&Bs[base + 8];
#pragma unroll
      for (int i = 0; i < 4; ++i) {
        a1[i][j] = mfma16(ah[i], bh, a1[i][j]);
        a2[i][j] = mfma16(ah[i], bl, a2[i][j]);
        a2[i][j] = mfma16(al[i], bh, a2[i][j]);
      }
    }
    __syncthreads();
  }
#pragma unroll
  for (int j = 0; j < 2; ++j) {
    int n = n0 + wn * 32 + j * 16 + lr;
    if (n < NV) {
#pragma unroll
      for (int i = 0; i < 4; ++i) {
        int row = wm * 64 + i * 16 + lk * 4;
#pragma unroll
        for (int r = 0; r < 4; ++r)
          out[(size_t)(row + r) * NV + n] =
              a1[i][j][r] + a2[i][j][r] * (1.f / 1024.f);
      }
    }
  }
}

extern "C" void kernel_launch(void* const* d_in, const int* in_sizes, int n_in,
                              void* d_out, int out_size, void* d_ws, size_t ws_size,
                              hipStream_t stream) {
  const int* ids = (const int*)d_in[0];
  const int* lens = (const int*)d_in[1];
  const float* emb = (const float*)d_in[2];
  const float* w_ih = (const float*)d_in[3];
  const float* w_hh = (const float*)d_in[4];
  const float* b_ih = (const float*)d_in[5];
  const float* b_hh = (const float*)d_in[6];
  float* out = (float*)d_out;

  char* ws = (char*)d_ws;
  __half* gates = (__half*)ws;                           // 78,643,200 B
  float* hfin = (float*)(ws + (size_t)B_ * T_ * G3 * sizeof(__half));
  unsigned int* whh_p =
      (unsigned int*)(ws + (size_t)B_ * T_ * G3 * sizeof(__half)
                      + (size_t)B_ * H_ * sizeof(float));   // 393,216 B
  unsigned int* wih_t = whh_p + (size_t)98304;              // 393,216 B

  pack_whh<<<dim3(384), dim3(256), 0, stream>>>(w_hh, whh_p);
  pack_wiht<<<dim3(384), dim3(256), 0, stream>>>(w_ih, wih_t);
  gates_mfma<<<dim3(400, 3), dim3(512), 0, stream>>>(
      ids, emb, (const __half*)wih_t, b_ih, gates);
  rec_kernel<<<dim3(B_), dim3(768), 0, stream>>>(lens, whh_p, b_hh, gates, hfin);
  logits_mfma<<<dim3((NV + 63) / 64), dim3(512), 0, stream>>>(hfin, emb, out);
}